// Round 1
// 1625.235 us; speedup vs baseline: 1.1929x; 1.1929x over previous
//
#include <hip/hip_runtime.h>
#include <hip/hip_fp16.h>

typedef _Float16 f16;
typedef _Float16 f16x8 __attribute__((ext_vector_type(8)));
typedef float    f32x4 __attribute__((ext_vector_type(4)));
typedef unsigned short ushort;
typedef unsigned int uint;
typedef unsigned long long u64;

__device__ __forceinline__ float sigm(float x) { return 1.f / (1.f + __expf(-x)); }
__device__ __forceinline__ float reluf(float x) { return x > 0.f ? x : 0.f; }
__device__ __forceinline__ float h2f(ushort u) { return (float)__builtin_bit_cast(f16, u); }
__device__ __forceinline__ ushort f2h(float v) { return __builtin_bit_cast(ushort, (f16)v); }

#define LDRLX(p)    __hip_atomic_load((p), __ATOMIC_RELAXED, __HIP_MEMORY_SCOPE_AGENT)
#define STRLX(p, v) __hip_atomic_store((p), (v), __ATOMIC_RELAXED, __HIP_MEMORY_SCOPE_AGENT)
#define MFMA16(a, b, c) __builtin_amdgcn_mfma_f32_16x16x32_f16((a), (b), (c), 0, 0, 0)

// Parallel multi-tag poll: lane i polls its own tag; one L2 round trip per
// iteration instead of one PER TAG (the old sequential wait_ge chains).
__device__ __forceinline__ void poll_all(uint* p, uint need, bool act) {
  bool done = !act;
  while (true) {
    if (!done) done = (LDRLX(p) >= need);
    if (__all((int)done)) break;
    __builtin_amdgcn_s_sleep(1);
  }
}

__device__ __forceinline__ u64 ldr64(const u64* p) {
  return __hip_atomic_load(p, __ATOMIC_RELAXED, __HIP_MEMORY_SCOPE_AGENT);
}
__device__ __forceinline__ void str64(u64* p, u64 v) {
  __hip_atomic_store(p, v, __ATOMIC_RELAXED, __HIP_MEMORY_SCOPE_AGENT);
}

// ---------------- pack B for MFMA b-frag layout (validated R1-R6)
template <int KF>
__global__ void pack_bsw(const float* __restrict__ B, f16* __restrict__ dst, int N) {
  int id = blockIdx.x * 256 + threadIdx.x;
  int total = KF * 32 * N;
  if (id >= total) return;
  int j  = id & 7;
  int L  = (id >> 3) & 63;
  int r  = id >> 9;
  int kf = r & (KF - 1);
  int c  = r / KF;
  int k  = kf * 32 + ((L >> 4) * 8) + j;
  int n  = c * 16 + (L & 15);
  dst[id] = (f16)B[k * N + n];
}

// ---------------- xW GEMM. MODE0 para: X[g][t][gate4][u256][s16]. MODE1 title:
// X[g][t][gate4][u128][s16].  (s = quad*4+r rows of the MFMA C tile = seq index)
template <int Sx, int K, int KF, int N, int NC, int MODE>
__global__ __launch_bounds__(256) void gemm_xw(const int* __restrict__ tok,
                                               const float* __restrict__ emb,
                                               const f16* __restrict__ Bsw,
                                               const float* __restrict__ bias,
                                               f16* __restrict__ X) {
  __shared__ int tokLds[64];
  __shared__ f16x8 bLds[8 * 64];
  const int tid = threadIdx.x;
  const int blk = blockIdx.x;
  const int g  = (MODE == 0) ? (blk >> 7) : (blk >> 4);
  const int t0 = (MODE == 0) ? ((blk & 127) * 4) : ((blk & 15) * 4);
  if (tid < 64) {
    int wv = tid >> 4, rho = tid & 15;
    tokLds[tid] = tok[(g * 16 + rho) * Sx + t0 + wv];
  }
  __syncthreads();
  const int wave = tid >> 6, lane = tid & 63;
  const int quad = lane >> 4, l16 = lane & 15;

  f16x8 a[KF];
  {
    const float* arow = emb + (long)tokLds[wave * 16 + l16] * K + quad * 8;
#pragma unroll
    for (int kf = 0; kf < KF; kf++) {
      float4 v0 = *(const float4*)(arow + kf * 32);
      float4 v1 = *(const float4*)(arow + kf * 32 + 4);
      f16x8 tv;
      tv[0] = (f16)v0.x; tv[1] = (f16)v0.y; tv[2] = (f16)v0.z; tv[3] = (f16)v0.w;
      tv[4] = (f16)v1.x; tv[5] = (f16)v1.y; tv[6] = (f16)v1.z; tv[7] = (f16)v1.w;
      a[kf] = tv;
    }
  }
  const int t = t0 + wave;
  const f16x8* Bfrag = (const f16x8*)Bsw;
  for (int c = 0; c < NC; c++) {
    for (int i = tid; i < KF * 64; i += 256) bLds[i] = Bfrag[c * KF * 64 + i];
    __syncthreads();
    f32x4 acc = {0.f, 0.f, 0.f, 0.f};
#pragma unroll
    for (int kf = 0; kf < KF; kf++)
      acc = MFMA16(a[kf], bLds[kf * 64 + lane], acc);
    const int col = c * 16 + l16;
    const float bc = bias[col];
    uint2 pk;
    pk.x = (uint)f2h(acc[0] + bc) | ((uint)f2h(acc[1] + bc) << 16);
    pk.y = (uint)f2h(acc[2] + bc) | ((uint)f2h(acc[3] + bc) << 16);
    size_t base;
    if (MODE == 0) {
      int gm = col >> 8, u = col & 255;
      base = (((size_t)(g * 512 + t) * 4 + gm) * 4096) + u * 16 + quad * 4;
    } else {
      int gm = col >> 7, u = col & 127;
      base = (((size_t)(g * 64 + t) * 4 + gm) * 2048) + u * 16 + quad * 4;
    }
    *(uint2*)(X + base) = pk;
    __syncthreads();
  }
}

// ---------------- init counters (must re-zero every replay)
__global__ void init_cnt(uint* __restrict__ cnt) {
  int i = blockIdx.x * 256 + threadIdx.x;
  if (i < 96 * 16) cnt[i] = 0u;
}

// ---------------- pipelined persistent recurrence: 96 blocks x 256 thr
// role = blk>>3, g = blk&7. roles: 0-3 paraL0(bb), 4-7 paraL1(bn), 8 paraL2,
// 9-10 titleL0(bb), 11 titleL1. Rings: relaxed 8B tagged publishes + per-role
// step counters (cnt, stride 16 uints). Tag stored after __syncthreads (vmcnt
// drain). Back-pressure every 4 steps keeps 8-slot rings safe.
// R7: all tag waits are PARALLEL (lane-distributed poll_all) — the old
// sequential wait_ge chains cost one L2 round trip per tag per step.
struct RP {
  const f16 *xp2, *xt2;
  const f16 *U0f, *W1f, *U1f, *W2f, *U2f, *U0tf, *W1tf, *U1tf;
  const float *pl1_b, *pl2_b, *tl1_b;
  const float *pd0W, *pd0b, *pd1W, *pd1b, *pd2W, *pd2b;
  const float *td0W, *td0b, *td1W, *td1b, *td2W, *td2b;
  uint *h0r, *h1r, *h0tr, *cnt;
  float* feat;
};

__global__ __launch_bounds__(256, 1) void recur_pipe(RP A) {
  __shared__ __align__(16) char smem[147968];
  const int tid = threadIdx.x;
  const int w = tid >> 6, lane = tid & 63;
  const int quad = lane >> 4, l16 = lane & 15;
  const int blk = blockIdx.x;
  const int role = blk >> 3, g = blk & 7;
  uint* mytag = A.cnt + (role * 8 + g) * 16;

  if (role < 4) {
    // ================= paragraph L0: units 64*bb.. , weights 128KB LDS =======
    const int bb = role;
    f16* wlds = (f16*)smem;                 // [gm4][wv4][kf8][64] f16x8
    f16* hb   = (f16*)(smem + 131072);      // [2][16*264]
    {
      const uint4* U0q = (const uint4*)A.U0f;
      uint4* wq = (uint4*)wlds;
      for (int idx = tid; idx < 8192; idx += 256) {
        int gm = idx >> 11, r = idx & 2047, wv = r >> 9, kf = (r >> 6) & 7, ln = r & 63;
        wq[idx] = U0q[((gm * 16 + 4 * bb + wv) * 8 + kf) * 64 + ln];
      }
    }
    for (int idx = tid; idx < 4224; idx += 256) hb[idx] = (f16)0.f;
    float c0[4] = {0.f, 0.f, 0.f, 0.f};
    uint* ringg = A.h0r + (size_t)g * 8 * 4096;
    int pp[3]; { int q = 0; for (int p = 0; p < 4; p++) if (p != bb) pp[q++] = p; }
    const uint2* xq2 = (const uint2*)A.xp2;
    const f16x8* wv8 = (const f16x8*)wlds;
    const int myu = 64 * bb + 16 * w + l16;
    // poll pointer: lanes 0-2 -> peer L0 tags, lanes 3-6 -> L1 backpressure
    uint* pollp = A.cnt;
    if (lane < 3) { int peer = lane + (lane >= bb ? 1 : 0); pollp = A.cnt + (peer * 8 + g) * 16; }
    else if (lane < 7) { pollp = A.cnt + ((4 + (lane - 3)) * 8 + g) * 16; }
    __syncthreads();

    for (int t = 0; t < 512; t++) {
      uint2 xv[4];
      {
        size_t xb = ((size_t)(g * 512 + t) * 4) * 1024 + (size_t)myu * 4 + quad;
#pragma unroll
        for (int gm = 0; gm < 4; gm++) xv[gm] = xq2[xb + (size_t)gm * 1024];
      }
      {
        uint need = 0; bool act = false;
        if (lane < 3) { act = (t > 0); need = (uint)t; }
        else if (lane < 7) { act = (t > 0) && ((t & 3) == 0); need = t > 4 ? (uint)(t - 4) : 0u; }
        poll_all(pollp, need, act);
      }
      if (t > 0) {
        f16* dst = hb + (t & 1) * 4224;
        const int ul = tid >> 2, s0 = (tid & 3) * 4;
        for (int q = 0; q < 3; q++) {
          const u64* reg = (const u64*)(ringg + (((t + 7) & 7) * 4 + pp[q]) * 1024);
          u64 v = ldr64(reg + tid);
#pragma unroll
          for (int j = 0; j < 4; j++)
            dst[(s0 + j) * 264 + pp[q] * 64 + ul] = __builtin_bit_cast(f16, (ushort)(v >> (16 * j)));
        }
      }
      __syncthreads();
      f16x8 af[8];
#pragma unroll
      for (int kf = 0; kf < 8; kf++)
        af[kf] = *(const f16x8*)&hb[(t & 1) * 4224 + l16 * 264 + kf * 32 + quad * 8];
      f32x4 z[4];
#pragma unroll
      for (int gm = 0; gm < 4; gm++) {
        f32x4 zz = {0.f, 0.f, 0.f, 0.f};
#pragma unroll
        for (int kf = 0; kf < 8; kf++)
          zz = MFMA16(af[kf], wv8[((gm * 4 + w) * 8 + kf) * 64 + lane], zz);
        z[gm] = zz;
      }
      u64 xs[4];
#pragma unroll
      for (int gm = 0; gm < 4; gm++) xs[gm] = ((u64)xv[gm].y << 32) | xv[gm].x;
      ushort hs[4];
      f16* wbuf = hb + ((t + 1) & 1) * 4224;
#pragma unroll
      for (int r = 0; r < 4; r++) {
        float gi = sigm(z[0][r] + h2f((ushort)(xs[0] >> (16 * r))));
        float ff = sigm(z[1][r] + h2f((ushort)(xs[1] >> (16 * r))));
        float gg = reluf(z[2][r] + h2f((ushort)(xs[2] >> (16 * r))));
        float oo = sigm(z[3][r] + h2f((ushort)(xs[3] >> (16 * r))));
        c0[r] = ff * c0[r] + gi * gg;
        hs[r] = f2h(oo * reluf(c0[r]));
        wbuf[(quad * 4 + r) * 264 + myu] = __builtin_bit_cast(f16, hs[r]);
      }
      {
        u64 pv = (u64)hs[0] | ((u64)hs[1] << 16) | ((u64)hs[2] << 32) | ((u64)hs[3] << 48);
        u64* wreg = (u64*)(ringg + ((t & 7) * 4 + bb) * 1024);
        str64(wreg + (16 * w + l16) * 4 + quad, pv);
      }
      __syncthreads();                 // drains vmcnt (all waves) before tag
      if (tid == 0) STRLX(mytag, (uint)(t + 1));
    }
  } else if (role < 8) {
    // ================= paragraph L1: units 32*bn.., 96KB LDS weights ========
    const int bn = role - 4;
    f16* wlds = (f16*)smem;                  // W1 @0 (4096 x f16x8), U1 @4096
    f16* h0c  = (f16*)(smem + 98304);        // 16*264
    f16* h1b  = (f16*)(smem + 106752);       // [2][16*136]
    float* zL = (float*)(smem + 115456);     // 16*132
    {
      const uint4* W1q = (const uint4*)A.W1f;
      const uint4* U1q = (const uint4*)A.U1f;
      uint4* wq = (uint4*)wlds;
      for (int idx = tid; idx < 4096; idx += 256) {
        int gm = idx >> 10, r = idx & 1023, j2 = r >> 9, kf = (r >> 6) & 7, ln = r & 63;
        wq[idx] = W1q[((gm * 8 + bn * 2 + j2) * 8 + kf) * 64 + ln];
      }
      for (int idx = tid; idx < 2048; idx += 256) {
        int gm = idx >> 9, r = idx & 511, j2 = r >> 8, kf = (r >> 6) & 3, ln = r & 63;
        wq[4096 + idx] = U1q[((gm * 8 + bn * 2 + j2) * 4 + kf) * 64 + ln];
      }
    }
    for (int idx = tid; idx < 2176; idx += 256) h1b[idx] = (f16)0.f;
    float c1[2] = {0.f, 0.f};
    float bth[4];
    { int un = tid & 31; for (int gm = 0; gm < 4; gm++) bth[gm] = A.pl1_b[gm * 128 + 32 * bn + un]; }
    uint* h0rg = A.h0r + (size_t)g * 8 * 4096;
    uint* h1rg = A.h1r + (size_t)g * 8 * 1024;
    int pp[3]; { int q = 0; for (int p = 0; p < 4; p++) if (p != bn) pp[q++] = p; }
    const f16x8* wv8 = (const f16x8*)wlds;
    // poll: lanes 0-3 -> L0 tags(t+1); 4-6 -> peer L1 tags(t); 7 -> L2 bp
    uint* pollp = A.cnt;
    if (lane < 4) { pollp = A.cnt + (lane * 8 + g) * 16; }
    else if (lane < 7) { int q = lane - 4; int peer = q + (q >= bn ? 1 : 0); pollp = A.cnt + ((4 + peer) * 8 + g) * 16; }
    else if (lane == 7) { pollp = A.cnt + (8 * 8 + g) * 16; }
    __syncthreads();

    for (int t = 0; t < 512; t++) {
      {
        uint need = 0; bool act = false;
        if (lane < 4) { act = true; need = (uint)(t + 1); }
        else if (lane < 7) { act = (t > 0); need = (uint)t; }
        else if (lane == 7) { act = ((t & 3) == 0); need = t > 4 ? (uint)(t - 4) : 0u; }
        poll_all(pollp, need, act);
      }
      {
        const u64* base = (const u64*)(h0rg + (t & 7) * 4096);
#pragma unroll
        for (int e = 0; e < 4; e++) {
          int idx = tid + 256 * e;
          u64 v = ldr64(base + idx);
          int q = idx >> 8, r = idx & 255, ul = r >> 2, s0 = (r & 3) * 4;
#pragma unroll
          for (int j = 0; j < 4; j++)
            h0c[(s0 + j) * 264 + q * 64 + ul] = __builtin_bit_cast(f16, (ushort)(v >> (16 * j)));
        }
      }
      if (t > 0 && tid < 128) {
        f16* dst = h1b + (t & 1) * 2176;
        const u64* sbase = (const u64*)(h1rg + ((t + 7) & 7) * 1024);
        const int ul = tid >> 2, s0 = (tid & 3) * 4;
        for (int q = 0; q < 3; q++) {
          u64 v = ldr64(sbase + pp[q] * 128 + tid);
#pragma unroll
          for (int j = 0; j < 4; j++)
            dst[(s0 + j) * 136 + pp[q] * 32 + ul] = __builtin_bit_cast(f16, (ushort)(v >> (16 * j)));
        }
      }
      __syncthreads();
      f16x8 af0[8], af1[4];
#pragma unroll
      for (int kf = 0; kf < 8; kf++)
        af0[kf] = *(const f16x8*)&h0c[l16 * 264 + kf * 32 + quad * 8];
#pragma unroll
      for (int kf = 0; kf < 4; kf++)
        af1[kf] = *(const f16x8*)&h1b[(t & 1) * 2176 + l16 * 136 + kf * 32 + quad * 8];
#pragma unroll
      for (int j2 = 0; j2 < 2; j2++) {
        f32x4 zz = {0.f, 0.f, 0.f, 0.f};
#pragma unroll
        for (int kf = 0; kf < 8; kf++)
          zz = MFMA16(af0[kf], wv8[((w * 2 + j2) * 8 + kf) * 64 + lane], zz);
#pragma unroll
        for (int kf = 0; kf < 4; kf++)
          zz = MFMA16(af1[kf], wv8[4096 + ((w * 2 + j2) * 4 + kf) * 64 + lane], zz);
#pragma unroll
        for (int r = 0; r < 4; r++)
          zL[(quad * 4 + r) * 132 + w * 32 + j2 * 16 + l16] = zz[r];
      }
      __syncthreads();
      {
        int sq = tid >> 5, un = tid & 31;
        f16* dst = h1b + ((t + 1) & 1) * 2176;
#pragma unroll
        for (int e = 0; e < 2; e++) {
          int s = sq + 8 * e;
          float gi = sigm(zL[s * 132 + un] + bth[0]);
          float ff = sigm(zL[s * 132 + 32 + un] + bth[1]);
          float gg = reluf(zL[s * 132 + 64 + un] + bth[2]);
          float oo = sigm(zL[s * 132 + 96 + un] + bth[3]);
          c1[e] = ff * c1[e] + gi * gg;
          dst[s * 136 + 32 * bn + un] = (f16)(oo * reluf(c1[e]));
        }
      }
      __syncthreads();
      if (tid < 128) {
        const f16* src = h1b + ((t + 1) & 1) * 2176;
        int ul = tid >> 2, s0 = (tid & 3) * 4;
        u64 pv = 0;
#pragma unroll
        for (int j = 0; j < 4; j++)
          pv |= (u64)__builtin_bit_cast(ushort, src[(s0 + j) * 136 + 32 * bn + ul]) << (16 * j);
        str64((u64*)(h1rg + (t & 7) * 1024) + bn * 128 + tid, pv);
      }
      __syncthreads();
      if (tid == 0) STRLX(mytag, (uint)(t + 1));
    }
  } else if (role == 8) {
    // ================= paragraph L2 + dense tail ============================
    f16* wlds = (f16*)smem;                  // W2 @0 (4096 f16x8), U2 @4096
    f16* h1c  = (f16*)(smem + 98304);        // 16*136
    f16* h2db = (f16*)(smem + 102656);       // [2][16*72]
    {
      const uint4* W2q = (const uint4*)A.W2f;
      const uint4* U2q = (const uint4*)A.U2f;
      uint4* wq = (uint4*)wlds;
      for (int idx = tid; idx < 4096; idx += 256) wq[idx] = W2q[idx];
      for (int idx = tid; idx < 2048; idx += 256) wq[4096 + idx] = U2q[idx];
    }
    for (int idx = tid; idx < 1152; idx += 256) h2db[idx] = (f16)0.f;
    float c2[4] = {0.f, 0.f, 0.f, 0.f};
    float b2[4];
#pragma unroll
    for (int gm = 0; gm < 4; gm++) b2[gm] = A.pl2_b[gm * 64 + 16 * w + l16];
    uint* h1rg = A.h1r + (size_t)g * 8 * 1024;
    const f16x8* wv8 = (const f16x8*)wlds;
    // poll: lanes 0-3 -> L1 tags(t+1)
    uint* pollp = A.cnt;
    if (lane < 4) pollp = A.cnt + ((4 + lane) * 8 + g) * 16;
    __syncthreads();

    for (int t = 0; t < 512; t++) {
      {
        uint need = (uint)(t + 1); bool act = (lane < 4);
        poll_all(pollp, need, act);
      }
      {
        const u64* base = (const u64*)(h1rg + (t & 7) * 1024);
#pragma unroll
        for (int e = 0; e < 2; e++) {
          int idx = tid + 256 * e;
          u64 v = ldr64(base + idx);
          int q = idx >> 7, r = idx & 127, ul = r >> 2, s0 = (r & 3) * 4;
#pragma unroll
          for (int j = 0; j < 4; j++)
            h1c[(s0 + j) * 136 + q * 32 + ul] = __builtin_bit_cast(f16, (ushort)(v >> (16 * j)));
        }
      }
      __syncthreads();
      f16x8 af0[4], af1[2];
#pragma unroll
      for (int kf = 0; kf < 4; kf++)
        af0[kf] = *(const f16x8*)&h1c[l16 * 136 + kf * 32 + quad * 8];
#pragma unroll
      for (int kf = 0; kf < 2; kf++)
        af1[kf] = *(const f16x8*)&h2db[(t & 1) * 1152 + l16 * 72 + kf * 32 + quad * 8];
      f32x4 z[4];
#pragma unroll
      for (int gm = 0; gm < 4; gm++) {
        f32x4 zz = {0.f, 0.f, 0.f, 0.f};
#pragma unroll
        for (int kf = 0; kf < 4; kf++)
          zz = MFMA16(af0[kf], wv8[((gm * 4 + w) * 4 + kf) * 64 + lane], zz);
#pragma unroll
        for (int kf = 0; kf < 2; kf++)
          zz = MFMA16(af1[kf], wv8[4096 + ((gm * 4 + w) * 2 + kf) * 64 + lane], zz);
        z[gm] = zz;
      }
#pragma unroll
      for (int r = 0; r < 4; r++) {
        float gi = sigm(z[0][r] + b2[0]);
        float ff = sigm(z[1][r] + b2[1]);
        float gg = reluf(z[2][r] + b2[2]);
        float oo = sigm(z[3][r] + b2[3]);
        c2[r] = ff * c2[r] + gi * gg;
        h2db[((t + 1) & 1) * 1152 + (quad * 4 + r) * 72 + 16 * w + l16] = (f16)(oo * reluf(c2[r]));
      }
      __syncthreads();
      if (tid == 0) STRLX(mytag, (uint)(t + 1));
    }
    __syncthreads();
    // dense tail -> feat cols 32..63
    float* zmA = (float*)smem;                // 16*132
    float* zmB = (float*)(smem + 8448);       // 16*68
    const f16* hf = h2db;                     // parity 0
#pragma unroll 1
    for (int e = 0; e < 8; e++) {
      const int idx = tid + 256 * e, sq = idx >> 7, j = idx & 127;
      float a = A.pd0b[j];
      for (int k = 0; k < 64; k++) a += (float)hf[sq * 72 + k] * A.pd0W[k * 128 + j];
      zmA[sq * 132 + j] = reluf(a);
    }
    __syncthreads();
#pragma unroll 1
    for (int e = 0; e < 4; e++) {
      const int idx = tid + 256 * e, sq = idx >> 6, j = idx & 63;
      float a = A.pd1b[j];
      for (int k = 0; k < 128; k++) a += zmA[sq * 132 + k] * A.pd1W[k * 64 + j];
      zmB[sq * 68 + j] = reluf(a);
    }
    __syncthreads();
#pragma unroll 1
    for (int e = 0; e < 2; e++) {
      const int idx = tid + 256 * e, sq = idx >> 5, j = idx & 31;
      float a = A.pd2b[j];
      for (int k = 0; k < 64; k++) a += zmB[sq * 68 + k] * A.pd2W[k * 32 + j];
      A.feat[(g * 16 + sq) * 64 + 32 + j] = a;
    }
  } else if (role < 11) {
    // ================= title L0: units 64*bb.., 64KB LDS ====================
    const int bb = role - 9;
    f16* wlds = (f16*)smem;                  // [gm4][wv4][kf4][64]
    f16* hb   = (f16*)(smem + 65536);        // [2][16*136]
    {
      const uint4* U0tq = (const uint4*)A.U0tf;
      uint4* wq = (uint4*)wlds;
      for (int idx = tid; idx < 4096; idx += 256) {
        int gm = idx >> 10, r = idx & 1023, wv = r >> 8, kf = (r >> 6) & 3, ln = r & 63;
        wq[idx] = U0tq[((gm * 8 + 4 * bb + wv) * 4 + kf) * 64 + ln];
      }
    }
    for (int idx = tid; idx < 2176; idx += 256) hb[idx] = (f16)0.f;
    float c0[4] = {0.f, 0.f, 0.f, 0.f};
    uint* ringg = A.h0tr + (size_t)g * 8 * 1024;
    const uint2* xq2 = (const uint2*)A.xt2;
    const f16x8* wv8 = (const f16x8*)wlds;
    const int myu = 64 * bb + 16 * w + l16;
    const int pb = bb ^ 1;
    // poll: lane 0 -> peer title-L0 tag(t); lane 1 -> title-L1 backpressure
    uint* pollp = A.cnt;
    if (lane == 0) pollp = A.cnt + ((9 + pb) * 8 + g) * 16;
    else if (lane == 1) pollp = A.cnt + (11 * 8 + g) * 16;
    __syncthreads();

    for (int t = 0; t < 64; t++) {
      uint2 xv[4];
      {
        size_t xb = ((size_t)(g * 64 + t) * 4) * 512 + (size_t)myu * 4 + quad;
#pragma unroll
        for (int gm = 0; gm < 4; gm++) xv[gm] = xq2[xb + (size_t)gm * 512];
      }
      {
        uint need = 0; bool act = false;
        if (lane == 0) { act = (t > 0); need = (uint)t; }
        else if (lane == 1) { act = (t > 0) && ((t & 3) == 0); need = t > 4 ? (uint)(t - 4) : 0u; }
        poll_all(pollp, need, act);
      }
      if (t > 0) {
        const u64* reg = (const u64*)(ringg + (((t + 7) & 7) * 2 + pb) * 512);
        u64 v = ldr64(reg + tid);
        f16* dst = hb + (t & 1) * 2176;
        int ul = tid >> 2, s0 = (tid & 3) * 4;
#pragma unroll
        for (int j = 0; j < 4; j++)
          dst[(s0 + j) * 136 + pb * 64 + ul] = __builtin_bit_cast(f16, (ushort)(v >> (16 * j)));
      }
      __syncthreads();
      f16x8 af[4];
#pragma unroll
      for (int kf = 0; kf < 4; kf++)
        af[kf] = *(const f16x8*)&hb[(t & 1) * 2176 + l16 * 136 + kf * 32 + quad * 8];
      f32x4 z[4];
#pragma unroll
      for (int gm = 0; gm < 4; gm++) {
        f32x4 zz = {0.f, 0.f, 0.f, 0.f};
#pragma unroll
        for (int kf = 0; kf < 4; kf++)
          zz = MFMA16(af[kf], wv8[((gm * 4 + w) * 4 + kf) * 64 + lane], zz);
        z[gm] = zz;
      }
      u64 xs[4];
#pragma unroll
      for (int gm = 0; gm < 4; gm++) xs[gm] = ((u64)xv[gm].y << 32) | xv[gm].x;
      ushort hs[4];
      f16* wbuf = hb + ((t + 1) & 1) * 2176;
#pragma unroll
      for (int r = 0; r < 4; r++) {
        float gi = sigm(z[0][r] + h2f((ushort)(xs[0] >> (16 * r))));
        float ff = sigm(z[1][r] + h2f((ushort)(xs[1] >> (16 * r))));
        float gg = reluf(z[2][r] + h2f((ushort)(xs[2] >> (16 * r))));
        float oo = sigm(z[3][r] + h2f((ushort)(xs[3] >> (16 * r))));
        c0[r] = ff * c0[r] + gi * gg;
        hs[r] = f2h(oo * reluf(c0[r]));
        wbuf[(quad * 4 + r) * 136 + myu] = __builtin_bit_cast(f16, hs[r]);
      }
      {
        u64 pv = (u64)hs[0] | ((u64)hs[1] << 16) | ((u64)hs[2] << 32) | ((u64)hs[3] << 48);
        u64* wreg = (u64*)(ringg + ((t & 7) * 2 + bb) * 512);
        str64(wreg + (16 * w + l16) * 4 + quad, pv);
      }
      __syncthreads();
      if (tid == 0) STRLX(mytag, (uint)(t + 1));
    }
  } else {
    // ================= title L1 + dense tail ================================
    f16* wlds = (f16*)smem;                  // W1t @0, U1t @4096 (f16x8 units)
    f16* h0tc = (f16*)(smem + 98304);        // 16*136
    f16* h1db = (f16*)(smem + 102656);       // [2][16*72]
    {
      const uint4* W1tq = (const uint4*)A.W1tf;
      const uint4* U1tq = (const uint4*)A.U1tf;
      uint4* wq = (uint4*)wlds;
      for (int idx = tid; idx < 4096; idx += 256) wq[idx] = W1tq[idx];
      for (int idx = tid; idx < 2048; idx += 256) wq[4096 + idx] = U1tq[idx];
    }
    for (int idx = tid; idx < 1152; idx += 256) h1db[idx] = (f16)0.f;
    float c1[4] = {0.f, 0.f, 0.f, 0.f};
    float bt[4];
#pragma unroll
    for (int gm = 0; gm < 4; gm++) bt[gm] = A.tl1_b[gm * 64 + 16 * w + l16];
    uint* ringg = A.h0tr + (size_t)g * 8 * 1024;
    const f16x8* wv8 = (const f16x8*)wlds;
    // poll: lanes 0-1 -> title-L0 tags(t+1)
    uint* pollp = A.cnt;
    if (lane < 2) pollp = A.cnt + ((9 + lane) * 8 + g) * 16;
    __syncthreads();

    for (int t = 0; t < 64; t++) {
      {
        uint need = (uint)(t + 1); bool act = (lane < 2);
        poll_all(pollp, need, act);
      }
      {
        const u64* base = (const u64*)(ringg + (t & 7) * 1024);
#pragma unroll
        for (int e = 0; e < 2; e++) {
          int idx = tid + 256 * e;
          u64 v = ldr64(base + idx);
          int q = idx >> 8, r = idx & 255, ul = r >> 2, s0 = (r & 3) * 4;
#pragma unroll
          for (int j = 0; j < 4; j++)
            h0tc[(s0 + j) * 136 + q * 64 + ul] = __builtin_bit_cast(f16, (ushort)(v >> (16 * j)));
        }
      }
      __syncthreads();
      f16x8 af0[4], af1[2];
#pragma unroll
      for (int kf = 0; kf < 4; kf++)
        af0[kf] = *(const f16x8*)&h0tc[l16 * 136 + kf * 32 + quad * 8];
#pragma unroll
      for (int kf = 0; kf < 2; kf++)
        af1[kf] = *(const f16x8*)&h1db[(t & 1) * 1152 + l16 * 72 + kf * 32 + quad * 8];
      f32x4 z[4];
#pragma unroll
      for (int gm = 0; gm < 4; gm++) {
        f32x4 zz = {0.f, 0.f, 0.f, 0.f};
#pragma unroll
        for (int kf = 0; kf < 4; kf++)
          zz = MFMA16(af0[kf], wv8[((gm * 4 + w) * 4 + kf) * 64 + lane], zz);
#pragma unroll
        for (int kf = 0; kf < 2; kf++)
          zz = MFMA16(af1[kf], wv8[4096 + ((gm * 4 + w) * 2 + kf) * 64 + lane], zz);
        z[gm] = zz;
      }
#pragma unroll
      for (int r = 0; r < 4; r++) {
        float gi = sigm(z[0][r] + bt[0]);
        float ff = sigm(z[1][r] + bt[1]);
        float gg = reluf(z[2][r] + bt[2]);
        float oo = sigm(z[3][r] + bt[3]);
        c1[r] = ff * c1[r] + gi * gg;
        h1db[((t + 1) & 1) * 1152 + (quad * 4 + r) * 72 + 16 * w + l16] = (f16)(oo * reluf(c1[r]));
      }
      __syncthreads();
      if (tid == 0) STRLX(mytag, (uint)(t + 1));
    }
    __syncthreads();
    // dense tail -> feat cols 0..31
    float* zmA = (float*)smem;
    float* zmB = (float*)(smem + 8448);
    const f16* hf = h1db;                    // parity 0
#pragma unroll 1
    for (int e = 0; e < 8; e++) {
      const int idx = tid + 256 * e, sq = idx >> 7, j = idx & 127;
      float a = A.td0b[j];
      for (int k = 0; k < 64; k++) a += (float)hf[sq * 72 + k] * A.td0W[k * 128 + j];
      zmA[sq * 132 + j] = reluf(a);
    }
    __syncthreads();
#pragma unroll 1
    for (int e = 0; e < 4; e++) {
      const int idx = tid + 256 * e, sq = idx >> 6, j = idx & 63;
      float a = A.td1b[j];
      for (int k = 0; k < 128; k++) a += zmA[sq * 132 + k] * A.td1W[k * 64 + j];
      zmB[sq * 68 + j] = reluf(a);
    }
    __syncthreads();
#pragma unroll 1
    for (int e = 0; e < 2; e++) {
      const int idx = tid + 256 * e, sq = idx >> 5, j = idx & 31;
      float a = A.td2b[j];
      for (int k = 0; k < 64; k++) a += zmB[sq * 68 + k] * A.td2W[k * 32 + j];
      A.feat[(g * 16 + sq) * 64 + j] = a;
    }
  }
}

// ---------------- head
__global__ __launch_bounds__(256) void head_kernel(const float* __restrict__ feat,
    const float* __restrict__ L0W, const float* __restrict__ L0b,
    const float* __restrict__ L1W, const float* __restrict__ L1b,
    const float* __restrict__ L2W, const float* __restrict__ L2b,
    const float* __restrict__ L3W, const float* __restrict__ L3b,
    float* __restrict__ out) {
  __shared__ float xb[512];
  __shared__ float y0[2048];
  __shared__ float y1[1024];
  __shared__ float y2[512];
  const int tid = threadIdx.x;
  for (int idx = tid; idx < 512; idx += 256) {
    int b = idx >> 6, d = idx & 63;
    float s = 0.f;
    for (int n = 0; n < 16; n++) s += feat[(b * 16 + n) * 64 + d];
    xb[idx] = s * (1.f / 16.f);
  }
  __syncthreads();
  for (int idx = tid; idx < 2048; idx += 256) {
    int b = idx >> 8, j = idx & 255;
    float a = L0b[j];
    for (int k = 0; k < 64; k++) a += xb[b * 64 + k] * L0W[k * 256 + j];
    y0[idx] = reluf(a);
  }
  __syncthreads();
  for (int idx = tid; idx < 1024; idx += 256) {
    int b = idx >> 7, j = idx & 127;
    float a = L1b[j];
    for (int k = 0; k < 256; k++) a += y0[b * 256 + k] * L1W[k * 128 + j];
    y1[idx] = reluf(a);
  }
  __syncthreads();
  for (int idx = tid; idx < 512; idx += 256) {
    int b = idx >> 6, j = idx & 63;
    float a = L2b[j];
    for (int k = 0; k < 128; k++) a += y1[b * 128 + k] * L2W[k * 64 + j];
    y2[idx] = reluf(a);
  }
  __syncthreads();
  {
    int b = tid >> 5, j = tid & 31;
    float a = L3b[j];
    for (int k = 0; k < 64; k++) a += y2[b * 64 + k] * L3W[k * 32 + j];
    out[b * 32 + j] = 1.f / (1.f + __expf(-a));
  }
}

extern "C" void kernel_launch(void* const* d_in, const int* in_sizes, int n_in,
                              void* d_out, int out_size, void* d_ws, size_t ws_size,
                              hipStream_t stream) {
  const int*   t_tok = (const int*)d_in[0];
  const int*   p_tok = (const int*)d_in[1];
  const float* emb_t = (const float*)d_in[2];
  const float* emb_p = (const float*)d_in[3];
  const float* tl0_W = (const float*)d_in[4];
  const float* tl0_U = (const float*)d_in[5];
  const float* tl0_b = (const float*)d_in[6];
  const float* tl1_W = (const float*)d_in[7];
  const float* tl1_U = (const float*)d_in[8];
  const float* tl1_b = (const float*)d_in[9];
  const float* td0_W = (const float*)d_in[10];
  const float* td0_b = (const float*)d_in[11];
  const float* td1_W = (const float*)d_in[12];
  const float* td1_b = (const float*)d_in[13];
  const float* td2_W = (const float*)d_in[14];
  const float* td2_b = (const float*)d_in[15];
  const float* pl0_W = (const float*)d_in[16];
  const float* pl0_U = (const float*)d_in[17];
  const float* pl0_b = (const float*)d_in[18];
  const float* pl1_W = (const float*)d_in[19];
  const float* pl1_U = (const float*)d_in[20];
  const float* pl1_b = (const float*)d_in[21];
  const float* pl2_W = (const float*)d_in[22];
  const float* pl2_U = (const float*)d_in[23];
  const float* pl2_b = (const float*)d_in[24];
  const float* pd0_W = (const float*)d_in[25];
  const float* pd0_b = (const float*)d_in[26];
  const float* pd1_W = (const float*)d_in[27];
  const float* pd1_b = (const float*)d_in[28];
  const float* pd2_W = (const float*)d_in[29];
  const float* pd2_b = (const float*)d_in[30];
  const float* L0_W  = (const float*)d_in[31];
  const float* L0_b  = (const float*)d_in[32];
  const float* L1_W  = (const float*)d_in[33];
  const float* L1_b  = (const float*)d_in[34];
  const float* L2_W  = (const float*)d_in[35];
  const float* L2_b  = (const float*)d_in[36];
  const float* L3_W  = (const float*)d_in[37];
  const float* L3_b  = (const float*)d_in[38];

  char* ws = (char*)d_ws;
  size_t off = 0;
  auto alloc = [&](size_t bytes) {
    void* ptr = ws + off;
    off += (bytes + 255) & ~(size_t)255;
    return ptr;
  };
  f16* xp2  = (f16*)alloc((size_t)8 * 512 * 4 * 4096 * 2);     // 128 MB
  f16* xt2  = (f16*)alloc((size_t)8 * 64 * 4 * 2048 * 2);      // 8 MB
  f16* Bp   = (f16*)alloc((size_t)256 * 1024 * 2);
  f16* Bt   = (f16*)alloc((size_t)128 * 512 * 2);
  f16* U0f  = (f16*)alloc((size_t)256 * 1024 * 2);
  f16* W1f  = (f16*)alloc((size_t)256 * 512 * 2);
  f16* U1f  = (f16*)alloc((size_t)128 * 512 * 2);
  f16* W2f  = (f16*)alloc((size_t)128 * 256 * 2);
  f16* U2f  = (f16*)alloc((size_t)64 * 256 * 2);
  f16* U0tf = (f16*)alloc((size_t)128 * 512 * 2);
  f16* W1tf = (f16*)alloc((size_t)128 * 256 * 2);
  f16* U1tf = (f16*)alloc((size_t)64 * 256 * 2);
  uint* h0r  = (uint*)alloc((size_t)8 * 8 * 4 * 1024 * 4);     // 1 MB
  uint* h1r  = (uint*)alloc((size_t)8 * 8 * 4 * 256 * 4);      // 256 KB
  uint* h0tr = (uint*)alloc((size_t)8 * 8 * 2 * 512 * 4);      // 256 KB
  uint* cnt  = (uint*)alloc((size_t)96 * 16 * 4);
  float* feat = (float*)alloc((size_t)128 * 64 * 4);

  init_cnt<<<6, 256, 0, stream>>>(cnt);

  pack_bsw<8><<<1024, 256, 0, stream>>>(pl0_W, Bp, 1024);
  pack_bsw<4><<<256, 256, 0, stream>>>(tl0_W, Bt, 512);
  pack_bsw<8><<<1024, 256, 0, stream>>>(pl0_U, U0f, 1024);
  pack_bsw<8><<<512, 256, 0, stream>>>(pl1_W, W1f, 512);
  pack_bsw<4><<<256, 256, 0, stream>>>(pl1_U, U1f, 512);
  pack_bsw<4><<<128, 256, 0, stream>>>(pl2_W, W2f, 256);
  pack_bsw<2><<<64, 256, 0, stream>>>(pl2_U, U2f, 256);
  pack_bsw<4><<<256, 256, 0, stream>>>(tl0_U, U0tf, 512);
  pack_bsw<4><<<128, 256, 0, stream>>>(tl1_W, W1tf, 256);
  pack_bsw<2><<<64, 256, 0, stream>>>(tl1_U, U1tf, 256);
  gemm_xw<512, 256, 8, 1024, 64, 0><<<1024, 256, 0, stream>>>(p_tok, emb_p, Bp, pl0_b, xp2);
  gemm_xw<64, 128, 4, 512, 32, 1><<<128, 256, 0, stream>>>(t_tok, emb_t, Bt, tl0_b, xt2);

  RP ra;
  ra.xp2 = xp2; ra.xt2 = xt2;
  ra.U0f = U0f; ra.W1f = W1f; ra.U1f = U1f; ra.W2f = W2f; ra.U2f = U2f;
  ra.U0tf = U0tf; ra.W1tf = W1tf; ra.U1tf = U1tf;
  ra.pl1_b = pl1_b; ra.pl2_b = pl2_b; ra.tl1_b = tl1_b;
  ra.pd0W = pd0_W; ra.pd0b = pd0_b; ra.pd1W = pd1_W; ra.pd1b = pd1_b;
  ra.pd2W = pd2_W; ra.pd2b = pd2_b;
  ra.td0W = td0_W; ra.td0b = td0_b; ra.td1W = td1_W; ra.td1b = td1_b;
  ra.td2W = td2_W; ra.td2b = td2_b;
  ra.h0r = h0r; ra.h1r = h1r; ra.h0tr = h0tr; ra.cnt = cnt;
  ra.feat = feat;
  recur_pipe<<<96, 256, 0, stream>>>(ra);

  head_kernel<<<1, 256, 0, stream>>>(feat, L0_W, L0_b, L1_W, L1_b, L2_W, L2_b,
                                     L3_W, L3_b, (float*)d_out);
}

// Round 2
// 1507.621 us; speedup vs baseline: 1.2860x; 1.0780x over previous
//
#include <hip/hip_runtime.h>
#include <hip/hip_fp16.h>

typedef _Float16 f16;
typedef _Float16 f16x8 __attribute__((ext_vector_type(8)));
typedef float    f32x4 __attribute__((ext_vector_type(4)));
typedef unsigned short ushort;
typedef unsigned int uint;
typedef unsigned long long u64;

__device__ __forceinline__ float sigm(float x) { return 1.f / (1.f + __expf(-x)); }
__device__ __forceinline__ float reluf(float x) { return x > 0.f ? x : 0.f; }
__device__ __forceinline__ float h2f(ushort u) { return (float)__builtin_bit_cast(f16, u); }
__device__ __forceinline__ ushort f2h(float v) { return __builtin_bit_cast(ushort, (f16)v); }

#define LDRLX(p)    __hip_atomic_load((p), __ATOMIC_RELAXED, __HIP_MEMORY_SCOPE_AGENT)
#define STRLX(p, v) __hip_atomic_store((p), (v), __ATOMIC_RELAXED, __HIP_MEMORY_SCOPE_AGENT)
#define MFMA16(a, b, c) __builtin_amdgcn_mfma_f32_16x16x32_f16((a), (b), (c), 0, 0, 0)

// Parallel multi-tag poll (backpressure only): lane i polls its own tag.
__device__ __forceinline__ void poll_all(uint* p, uint need, bool act) {
  bool done = !act;
  while (true) {
    if (!done) done = (LDRLX(p) >= need);
    if (__all((int)done)) break;
    __builtin_amdgcn_s_sleep(1);
  }
}

__device__ __forceinline__ u64 ldr64(const u64* p) {
  return __hip_atomic_load(p, __ATOMIC_RELAXED, __HIP_MEMORY_SCOPE_AGENT);
}
__device__ __forceinline__ void str64(u64* p, u64 v) {
  __hip_atomic_store(p, v, __ATOMIC_RELAXED, __HIP_MEMORY_SCOPE_AGENT);
}

// Tag-in-data record poll: each u64 record = {tag:32 | payload(2xf16):32}.
// All records are loaded in parallel per pass (pipelined RTTs); only stale
// ones are re-loaded. nd[i]==0 => record skipped (payload unused at t==0).
template <int NR>
__device__ __forceinline__ void poll_recs(const u64* const (&ra)[NR],
                                          const uint (&nd)[NR], u64 (&rv)[NR]) {
  bool ok[NR];
#pragma unroll
  for (int i = 0; i < NR; i++) ok[i] = (nd[i] == 0u);
  while (true) {
    bool all = true;
#pragma unroll
    for (int i = 0; i < NR; i++) if (!ok[i]) rv[i] = ldr64(ra[i]);
#pragma unroll
    for (int i = 0; i < NR; i++) if (!ok[i]) ok[i] = ((uint)(rv[i] >> 32) >= nd[i]);
#pragma unroll
    for (int i = 0; i < NR; i++) all &= ok[i];
    if (all) return;
    __builtin_amdgcn_s_sleep(1);
  }
}

// ---------------- pack B for MFMA b-frag layout (validated R1-R6)
template <int KF>
__global__ void pack_bsw(const float* __restrict__ B, f16* __restrict__ dst, int N) {
  int id = blockIdx.x * 256 + threadIdx.x;
  int total = KF * 32 * N;
  if (id >= total) return;
  int j  = id & 7;
  int L  = (id >> 3) & 63;
  int r  = id >> 9;
  int kf = r & (KF - 1);
  int c  = r / KF;
  int k  = kf * 32 + ((L >> 4) * 8) + j;
  int n  = c * 16 + (L & 15);
  dst[id] = (f16)B[k * N + n];
}

// ---------------- xW GEMM. MODE0 para: X[g][t][gate4][u256][s16]. MODE1 title:
// X[g][t][gate4][u128][s16].  (s = quad*4+r rows of the MFMA C tile = seq index)
template <int Sx, int K, int KF, int N, int NC, int MODE>
__global__ __launch_bounds__(256) void gemm_xw(const int* __restrict__ tok,
                                               const float* __restrict__ emb,
                                               const f16* __restrict__ Bsw,
                                               const float* __restrict__ bias,
                                               f16* __restrict__ X) {
  __shared__ int tokLds[64];
  __shared__ f16x8 bLds[8 * 64];
  const int tid = threadIdx.x;
  const int blk = blockIdx.x;
  const int g  = (MODE == 0) ? (blk >> 7) : (blk >> 4);
  const int t0 = (MODE == 0) ? ((blk & 127) * 4) : ((blk & 15) * 4);
  if (tid < 64) {
    int wv = tid >> 4, rho = tid & 15;
    tokLds[tid] = tok[(g * 16 + rho) * Sx + t0 + wv];
  }
  __syncthreads();
  const int wave = tid >> 6, lane = tid & 63;
  const int quad = lane >> 4, l16 = lane & 15;

  f16x8 a[KF];
  {
    const float* arow = emb + (long)tokLds[wave * 16 + l16] * K + quad * 8;
#pragma unroll
    for (int kf = 0; kf < KF; kf++) {
      float4 v0 = *(const float4*)(arow + kf * 32);
      float4 v1 = *(const float4*)(arow + kf * 32 + 4);
      f16x8 tv;
      tv[0] = (f16)v0.x; tv[1] = (f16)v0.y; tv[2] = (f16)v0.z; tv[3] = (f16)v0.w;
      tv[4] = (f16)v1.x; tv[5] = (f16)v1.y; tv[6] = (f16)v1.z; tv[7] = (f16)v1.w;
      a[kf] = tv;
    }
  }
  const int t = t0 + wave;
  const f16x8* Bfrag = (const f16x8*)Bsw;
  for (int c = 0; c < NC; c++) {
    for (int i = tid; i < KF * 64; i += 256) bLds[i] = Bfrag[c * KF * 64 + i];
    __syncthreads();
    f32x4 acc = {0.f, 0.f, 0.f, 0.f};
#pragma unroll
    for (int kf = 0; kf < KF; kf++)
      acc = MFMA16(a[kf], bLds[kf * 64 + lane], acc);
    const int col = c * 16 + l16;
    const float bc = bias[col];
    uint2 pk;
    pk.x = (uint)f2h(acc[0] + bc) | ((uint)f2h(acc[1] + bc) << 16);
    pk.y = (uint)f2h(acc[2] + bc) | ((uint)f2h(acc[3] + bc) << 16);
    size_t base;
    if (MODE == 0) {
      int gm = col >> 8, u = col & 255;
      base = (((size_t)(g * 512 + t) * 4 + gm) * 4096) + u * 16 + quad * 4;
    } else {
      int gm = col >> 7, u = col & 127;
      base = (((size_t)(g * 64 + t) * 4 + gm) * 2048) + u * 16 + quad * 4;
    }
    *(uint2*)(X + base) = pk;
    __syncthreads();
  }
}

// ---------------- pipelined persistent recurrence: 96 blocks x 256 thr
// role = blk>>3, g = blk&7. roles: 0-3 paraL0(bb), 4-7 paraL1(bn), 8 paraL2,
// 9-10 titleL0(bb), 11 titleL1.
// R8 protocol: TAG-IN-DATA rings. Every u64 record = {step_tag:32|2xf16:32},
// stored with one atomic str64 right after the producing thread computes the
// values (no pre-publish barrier, no vmcnt drain, no separate tag store).
// Consumers poll their own records (parallel loads, stale-only reload) —
// discovery and payload arrive in the same L3 round trip. cnt[] counters are
// retained ONLY for cross-stage backpressure (consumers L1/L2/tL1 publish
// consumption progress; producers check every 4 steps). Peer-ring overwrite
// safety: mutual data dependency bounds peer drift to <=1 step; cross-stage
// gated by cnt >= t-4 (8-slot rings). Rings are zeroed each replay via
// hipMemsetAsync (stale tags from a prior replay would false-validate).
// Record maps:
//   h0r  (paraL0):  g*16384 + slot*2048 + bb*512 + unit_local*8 + rowpair
//                   payload rows (2*rp, 2*rp+1)             [rp = quad*2+j]
//   h1r  (paraL1):  g*8192  + slot*1024 + bn*256 + un*8 + sq
//                   payload rows (sq, sq+8)
//   h0tr (titleL0): g*8192  + slot*1024 + bb*512 + unit_local*8 + rowpair
struct RP {
  const f16 *xp2, *xt2;
  const f16 *U0f, *W1f, *U1f, *W2f, *U2f, *U0tf, *W1tf, *U1tf;
  const float *pl1_b, *pl2_b, *tl1_b;
  const float *pd0W, *pd0b, *pd1W, *pd1b, *pd2W, *pd2b;
  const float *td0W, *td0b, *td1W, *td1b, *td2W, *td2b;
  u64 *h0r, *h1r, *h0tr;
  uint *cnt;
  float* feat;
};

__global__ __launch_bounds__(256, 1) void recur_pipe(RP A) {
  __shared__ __align__(16) char smem[147968];
  const int tid = threadIdx.x;
  const int w = tid >> 6, lane = tid & 63;
  const int quad = lane >> 4, l16 = lane & 15;
  const int blk = blockIdx.x;
  const int role = blk >> 3, g = blk & 7;
  uint* mytag = A.cnt + (role * 8 + g) * 16;

  if (role < 4) {
    // ================= paragraph L0: units 64*bb.. , weights 128KB LDS =======
    const int bb = role;
    f16* wlds = (f16*)smem;                 // [gm4][wv4][kf8][64] f16x8
    f16* hb   = (f16*)(smem + 131072);      // [2][16*264]
    {
      const uint4* U0q = (const uint4*)A.U0f;
      uint4* wq = (uint4*)wlds;
      for (int idx = tid; idx < 8192; idx += 256) {
        int gm = idx >> 11, r = idx & 2047, wv = r >> 9, kf = (r >> 6) & 7, ln = r & 63;
        wq[idx] = U0q[((gm * 16 + 4 * bb + wv) * 8 + kf) * 64 + ln];
      }
    }
    for (int idx = tid; idx < 4224; idx += 256) hb[idx] = (f16)0.f;
    float c0[4] = {0.f, 0.f, 0.f, 0.f};
    u64* ringg = A.h0r + (size_t)g * 16384;
    int pp[3]; { int q = 0; for (int p = 0; p < 4; p++) if (p != bb) pp[q++] = p; }
    const uint2* xq2 = (const uint2*)A.xp2;
    const f16x8* wv8 = (const f16x8*)wlds;
    const int myu = 64 * bb + 16 * w + l16;
    uint* bpp = A.cnt;
    if (lane < 4) bpp = A.cnt + ((4 + lane) * 8 + g) * 16;
    __syncthreads();

    for (int t = 0; t < 512; t++) {
      uint2 xv[4];
      {
        size_t xb = ((size_t)(g * 512 + t) * 4) * 1024 + (size_t)myu * 4 + quad;
#pragma unroll
        for (int gm = 0; gm < 4; gm++) xv[gm] = xq2[xb + (size_t)gm * 1024];
      }
      {
        bool act = (lane < 4) && (t > 0) && ((t & 3) == 0);
        uint need = t > 4 ? (uint)(t - 4) : 0u;
        poll_all(bpp, need, act);
      }
      {
        const u64* slotb = ringg + (size_t)((t + 7) & 7) * 2048;
        const u64* ra[6]; uint nd[6]; u64 rv[6];
#pragma unroll
        for (int q = 0; q < 3; q++) {
          const u64* rb = slotb + pp[q] * 512 + 2 * tid;
          ra[q * 2] = rb; ra[q * 2 + 1] = rb + 1;
          nd[q * 2] = nd[q * 2 + 1] = (t > 0) ? (uint)t : 0u;
        }
        poll_recs<6>(ra, nd, rv);
        if (t > 0) {
          f16* dst = hb + (t & 1) * 4224;
          const int ul = tid >> 2;
#pragma unroll
          for (int q = 0; q < 3; q++)
#pragma unroll
            for (int j = 0; j < 2; j++) {
              uint pay = (uint)rv[q * 2 + j];
              int r0 = ((tid & 3) * 2 + j) * 2;
              dst[r0 * 264 + pp[q] * 64 + ul] = __builtin_bit_cast(f16, (ushort)pay);
              dst[(r0 + 1) * 264 + pp[q] * 64 + ul] = __builtin_bit_cast(f16, (ushort)(pay >> 16));
            }
        }
      }
      __syncthreads();
      f16x8 af[8];
#pragma unroll
      for (int kf = 0; kf < 8; kf++)
        af[kf] = *(const f16x8*)&hb[(t & 1) * 4224 + l16 * 264 + kf * 32 + quad * 8];
      f32x4 z[4];
#pragma unroll
      for (int gm = 0; gm < 4; gm++) {
        f32x4 zz = {0.f, 0.f, 0.f, 0.f};
#pragma unroll
        for (int kf = 0; kf < 8; kf++)
          zz = MFMA16(af[kf], wv8[((gm * 4 + w) * 8 + kf) * 64 + lane], zz);
        z[gm] = zz;
      }
      u64 xs[4];
#pragma unroll
      for (int gm = 0; gm < 4; gm++) xs[gm] = ((u64)xv[gm].y << 32) | xv[gm].x;
      ushort hs[4];
      f16* wbuf = hb + ((t + 1) & 1) * 4224;
#pragma unroll
      for (int r = 0; r < 4; r++) {
        float gi = sigm(z[0][r] + h2f((ushort)(xs[0] >> (16 * r))));
        float ff = sigm(z[1][r] + h2f((ushort)(xs[1] >> (16 * r))));
        float gg = reluf(z[2][r] + h2f((ushort)(xs[2] >> (16 * r))));
        float oo = sigm(z[3][r] + h2f((ushort)(xs[3] >> (16 * r))));
        c0[r] = ff * c0[r] + gi * gg;
        hs[r] = f2h(oo * reluf(c0[r]));
        wbuf[(quad * 4 + r) * 264 + myu] = __builtin_bit_cast(f16, hs[r]);
      }
      {
        u64 tg = ((u64)(uint)(t + 1)) << 32;
        u64* wb = ringg + (size_t)(t & 7) * 2048 + bb * 512 + (16 * w + l16) * 8 + quad * 2;
        str64(wb,     tg | (u64)((uint)hs[0] | ((uint)hs[1] << 16)));
        str64(wb + 1, tg | (u64)((uint)hs[2] | ((uint)hs[3] << 16)));
      }
    }
  } else if (role < 8) {
    // ================= paragraph L1: units 32*bn.., 96KB LDS weights ========
    const int bn = role - 4;
    f16* wlds = (f16*)smem;                  // W1 @0 (4096 x f16x8), U1 @4096
    f16* h0c  = (f16*)(smem + 98304);        // 16*264
    f16* h1b  = (f16*)(smem + 106752);       // [2][16*136]
    float* zL = (float*)(smem + 115456);     // 16*132
    {
      const uint4* W1q = (const uint4*)A.W1f;
      const uint4* U1q = (const uint4*)A.U1f;
      uint4* wq = (uint4*)wlds;
      for (int idx = tid; idx < 4096; idx += 256) {
        int gm = idx >> 10, r = idx & 1023, j2 = r >> 9, kf = (r >> 6) & 7, ln = r & 63;
        wq[idx] = W1q[((gm * 8 + bn * 2 + j2) * 8 + kf) * 64 + ln];
      }
      for (int idx = tid; idx < 2048; idx += 256) {
        int gm = idx >> 9, r = idx & 511, j2 = r >> 8, kf = (r >> 6) & 3, ln = r & 63;
        wq[4096 + idx] = U1q[((gm * 8 + bn * 2 + j2) * 4 + kf) * 64 + ln];
      }
    }
    for (int idx = tid; idx < 2176; idx += 256) h1b[idx] = (f16)0.f;
    float c1[2] = {0.f, 0.f};
    float bth[4];
    { int un = tid & 31; for (int gm = 0; gm < 4; gm++) bth[gm] = A.pl1_b[gm * 128 + 32 * bn + un]; }
    u64* h0rg = A.h0r + (size_t)g * 16384;
    u64* h1rg = A.h1r + (size_t)g * 8192;
    int pp[3]; { int q = 0; for (int p = 0; p < 4; p++) if (p != bn) pp[q++] = p; }
    const f16x8* wv8 = (const f16x8*)wlds;
    uint* bpp = A.cnt + (8 * 8 + g) * 16;
    __syncthreads();

    for (int t = 0; t < 512; t++) {
      {
        bool act = (lane == 0) && ((t & 3) == 0);
        uint need = t > 4 ? (uint)(t - 4) : 0u;
        poll_all(bpp, need, act);
      }
      const u64* ra[11]; uint nd[11]; u64 rv[11];
      {
        const u64* s0b = h0rg + (size_t)(t & 7) * 2048;
#pragma unroll
        for (int e = 0; e < 8; e++) { ra[e] = s0b + tid + 256 * e; nd[e] = (uint)(t + 1); }
        const u64* s1b = h1rg + (size_t)((t + 7) & 7) * 1024;
#pragma unroll
        for (int q = 0; q < 3; q++) { ra[8 + q] = s1b + pp[q] * 256 + tid; nd[8 + q] = (t > 0) ? (uint)t : 0u; }
      }
      poll_recs<11>(ra, nd, rv);
      {
#pragma unroll
        for (int e = 0; e < 8; e++) {
          int idx = tid + 256 * e;
          int q = idx >> 9, rr = idx & 511, uls = rr >> 3, rp = rr & 7;
          uint pay = (uint)rv[e];
          h0c[(2 * rp) * 264 + q * 64 + uls]     = __builtin_bit_cast(f16, (ushort)pay);
          h0c[(2 * rp + 1) * 264 + q * 64 + uls] = __builtin_bit_cast(f16, (ushort)(pay >> 16));
        }
        if (t > 0) {
          f16* dst = h1b + (t & 1) * 2176;
          int un = tid >> 3, sq = tid & 7;
#pragma unroll
          for (int q = 0; q < 3; q++) {
            uint pay = (uint)rv[8 + q];
            dst[sq * 136 + pp[q] * 32 + un]       = __builtin_bit_cast(f16, (ushort)pay);
            dst[(sq + 8) * 136 + pp[q] * 32 + un] = __builtin_bit_cast(f16, (ushort)(pay >> 16));
          }
        }
      }
      __syncthreads();
      if (tid == 0) STRLX(mytag, (uint)(t + 1));    // consumption signal (bp)
      f16x8 af0[8], af1[4];
#pragma unroll
      for (int kf = 0; kf < 8; kf++)
        af0[kf] = *(const f16x8*)&h0c[l16 * 264 + kf * 32 + quad * 8];
#pragma unroll
      for (int kf = 0; kf < 4; kf++)
        af1[kf] = *(const f16x8*)&h1b[(t & 1) * 2176 + l16 * 136 + kf * 32 + quad * 8];
#pragma unroll
      for (int j2 = 0; j2 < 2; j2++) {
        f32x4 zz = {0.f, 0.f, 0.f, 0.f};
#pragma unroll
        for (int kf = 0; kf < 8; kf++)
          zz = MFMA16(af0[kf], wv8[((w * 2 + j2) * 8 + kf) * 64 + lane], zz);
#pragma unroll
        for (int kf = 0; kf < 4; kf++)
          zz = MFMA16(af1[kf], wv8[4096 + ((w * 2 + j2) * 4 + kf) * 64 + lane], zz);
#pragma unroll
        for (int r = 0; r < 4; r++)
          zL[(quad * 4 + r) * 132 + w * 32 + j2 * 16 + l16] = zz[r];
      }
      __syncthreads();
      {
        int sq = tid >> 5, un = tid & 31;
        f16* dst = h1b + ((t + 1) & 1) * 2176;
        ushort hh[2];
#pragma unroll
        for (int e = 0; e < 2; e++) {
          int s = sq + 8 * e;
          float gi = sigm(zL[s * 132 + un] + bth[0]);
          float ff = sigm(zL[s * 132 + 32 + un] + bth[1]);
          float gg = reluf(zL[s * 132 + 64 + un] + bth[2]);
          float oo = sigm(zL[s * 132 + 96 + un] + bth[3]);
          c1[e] = ff * c1[e] + gi * gg;
          float hv = oo * reluf(c1[e]);
          hh[e] = f2h(hv);
          dst[s * 136 + 32 * bn + un] = __builtin_bit_cast(f16, hh[e]);
        }
        u64 tg = ((u64)(uint)(t + 1)) << 32;
        str64(h1rg + (size_t)(t & 7) * 1024 + bn * 256 + un * 8 + sq,
              tg | (u64)((uint)hh[0] | ((uint)hh[1] << 16)));
      }
    }
  } else if (role == 8) {
    // ================= paragraph L2 + dense tail ============================
    f16* wlds = (f16*)smem;                  // W2 @0 (4096 f16x8), U2 @4096
    f16* h1c  = (f16*)(smem + 98304);        // [2][16*136]
    f16* h2db = (f16*)(smem + 107008);       // [2][16*72]
    {
      const uint4* W2q = (const uint4*)A.W2f;
      const uint4* U2q = (const uint4*)A.U2f;
      uint4* wq = (uint4*)wlds;
      for (int idx = tid; idx < 4096; idx += 256) wq[idx] = W2q[idx];
      for (int idx = tid; idx < 2048; idx += 256) wq[4096 + idx] = U2q[idx];
    }
    for (int idx = tid; idx < 1152; idx += 256) h2db[idx] = (f16)0.f;
    float c2[4] = {0.f, 0.f, 0.f, 0.f};
    float b2[4];
#pragma unroll
    for (int gm = 0; gm < 4; gm++) b2[gm] = A.pl2_b[gm * 64 + 16 * w + l16];
    u64* h1rg = A.h1r + (size_t)g * 8192;
    const f16x8* wv8 = (const f16x8*)wlds;
    __syncthreads();

    for (int t = 0; t < 512; t++) {
      const u64* ra[4]; uint nd[4]; u64 rv[4];
      {
        const u64* s1b = h1rg + (size_t)(t & 7) * 1024;
#pragma unroll
        for (int e = 0; e < 4; e++) { ra[e] = s1b + tid + 256 * e; nd[e] = (uint)(t + 1); }
      }
      poll_recs<4>(ra, nd, rv);
      {
        f16* dst = h1c + (t & 1) * 2176;
#pragma unroll
        for (int e = 0; e < 4; e++) {
          int idx = tid + 256 * e;
          int bq = idx >> 8, rr = idx & 255, un = rr >> 3, sq = rr & 7;
          uint pay = (uint)rv[e];
          dst[sq * 136 + bq * 32 + un]       = __builtin_bit_cast(f16, (ushort)pay);
          dst[(sq + 8) * 136 + bq * 32 + un] = __builtin_bit_cast(f16, (ushort)(pay >> 16));
        }
      }
      __syncthreads();
      if (tid == 0) STRLX(mytag, (uint)(t + 1));    // consumption signal (bp)
      f16x8 af0[4], af1[2];
#pragma unroll
      for (int kf = 0; kf < 4; kf++)
        af0[kf] = *(const f16x8*)&h1c[(t & 1) * 2176 + l16 * 136 + kf * 32 + quad * 8];
#pragma unroll
      for (int kf = 0; kf < 2; kf++)
        af1[kf] = *(const f16x8*)&h2db[(t & 1) * 1152 + l16 * 72 + kf * 32 + quad * 8];
      f32x4 z[4];
#pragma unroll
      for (int gm = 0; gm < 4; gm++) {
        f32x4 zz = {0.f, 0.f, 0.f, 0.f};
#pragma unroll
        for (int kf = 0; kf < 4; kf++)
          zz = MFMA16(af0[kf], wv8[((gm * 4 + w) * 4 + kf) * 64 + lane], zz);
#pragma unroll
        for (int kf = 0; kf < 2; kf++)
          zz = MFMA16(af1[kf], wv8[4096 + ((gm * 4 + w) * 2 + kf) * 64 + lane], zz);
        z[gm] = zz;
      }
#pragma unroll
      for (int r = 0; r < 4; r++) {
        float gi = sigm(z[0][r] + b2[0]);
        float ff = sigm(z[1][r] + b2[1]);
        float gg = reluf(z[2][r] + b2[2]);
        float oo = sigm(z[3][r] + b2[3]);
        c2[r] = ff * c2[r] + gi * gg;
        h2db[((t + 1) & 1) * 1152 + (quad * 4 + r) * 72 + 16 * w + l16] = (f16)(oo * reluf(c2[r]));
      }
    }
    __syncthreads();
    // dense tail -> feat cols 32..63
    float* zmA = (float*)smem;                // 16*132
    float* zmB = (float*)(smem + 8448);       // 16*68
    const f16* hf = h2db;                     // parity 0
#pragma unroll 1
    for (int e = 0; e < 8; e++) {
      const int idx = tid + 256 * e, sq = idx >> 7, j = idx & 127;
      float a = A.pd0b[j];
      for (int k = 0; k < 64; k++) a += (float)hf[sq * 72 + k] * A.pd0W[k * 128 + j];
      zmA[sq * 132 + j] = reluf(a);
    }
    __syncthreads();
#pragma unroll 1
    for (int e = 0; e < 4; e++) {
      const int idx = tid + 256 * e, sq = idx >> 6, j = idx & 63;
      float a = A.pd1b[j];
      for (int k = 0; k < 128; k++) a += zmA[sq * 132 + k] * A.pd1W[k * 64 + j];
      zmB[sq * 68 + j] = reluf(a);
    }
    __syncthreads();
#pragma unroll 1
    for (int e = 0; e < 2; e++) {
      const int idx = tid + 256 * e, sq = idx >> 5, j = idx & 31;
      float a = A.pd2b[j];
      for (int k = 0; k < 64; k++) a += zmB[sq * 68 + k] * A.pd2W[k * 32 + j];
      A.feat[(g * 16 + sq) * 64 + 32 + j] = a;
    }
  } else if (role < 11) {
    // ================= title L0: units 64*bb.., 64KB LDS ====================
    const int bb = role - 9;
    f16* wlds = (f16*)smem;                  // [gm4][wv4][kf4][64]
    f16* hb   = (f16*)(smem + 65536);        // [2][16*136]
    {
      const uint4* U0tq = (const uint4*)A.U0tf;
      uint4* wq = (uint4*)wlds;
      for (int idx = tid; idx < 4096; idx += 256) {
        int gm = idx >> 10, r = idx & 1023, wv = r >> 8, kf = (r >> 6) & 3, ln = r & 63;
        wq[idx] = U0tq[((gm * 8 + 4 * bb + wv) * 4 + kf) * 64 + ln];
      }
    }
    for (int idx = tid; idx < 2176; idx += 256) hb[idx] = (f16)0.f;
    float c0[4] = {0.f, 0.f, 0.f, 0.f};
    u64* ringg = A.h0tr + (size_t)g * 8192;
    const uint2* xq2 = (const uint2*)A.xt2;
    const f16x8* wv8 = (const f16x8*)wlds;
    const int myu = 64 * bb + 16 * w + l16;
    const int pbb = bb ^ 1;
    uint* bpp = A.cnt + (11 * 8 + g) * 16;
    __syncthreads();

    for (int t = 0; t < 64; t++) {
      uint2 xv[4];
      {
        size_t xb = ((size_t)(g * 64 + t) * 4) * 512 + (size_t)myu * 4 + quad;
#pragma unroll
        for (int gm = 0; gm < 4; gm++) xv[gm] = xq2[xb + (size_t)gm * 512];
      }
      {
        bool act = (lane == 0) && (t > 0) && ((t & 3) == 0);
        uint need = t > 4 ? (uint)(t - 4) : 0u;
        poll_all(bpp, need, act);
      }
      {
        const u64* ra[2]; uint nd[2]; u64 rv[2];
        const u64* rb = ringg + (size_t)((t + 7) & 7) * 1024 + pbb * 512 + 2 * tid;
        ra[0] = rb; ra[1] = rb + 1;
        nd[0] = nd[1] = (t > 0) ? (uint)t : 0u;
        poll_recs<2>(ra, nd, rv);
        if (t > 0) {
          f16* dst = hb + (t & 1) * 2176;
          const int ul = tid >> 2;
#pragma unroll
          for (int j = 0; j < 2; j++) {
            uint pay = (uint)rv[j];
            int r0 = ((tid & 3) * 2 + j) * 2;
            dst[r0 * 136 + pbb * 64 + ul]       = __builtin_bit_cast(f16, (ushort)pay);
            dst[(r0 + 1) * 136 + pbb * 64 + ul] = __builtin_bit_cast(f16, (ushort)(pay >> 16));
          }
        }
      }
      __syncthreads();
      f16x8 af[4];
#pragma unroll
      for (int kf = 0; kf < 4; kf++)
        af[kf] = *(const f16x8*)&hb[(t & 1) * 2176 + l16 * 136 + kf * 32 + quad * 8];
      f32x4 z[4];
#pragma unroll
      for (int gm = 0; gm < 4; gm++) {
        f32x4 zz = {0.f, 0.f, 0.f, 0.f};
#pragma unroll
        for (int kf = 0; kf < 4; kf++)
          zz = MFMA16(af[kf], wv8[((gm * 4 + w) * 4 + kf) * 64 + lane], zz);
        z[gm] = zz;
      }
      u64 xs[4];
#pragma unroll
      for (int gm = 0; gm < 4; gm++) xs[gm] = ((u64)xv[gm].y << 32) | xv[gm].x;
      ushort hs[4];
      f16* wbuf = hb + ((t + 1) & 1) * 2176;
#pragma unroll
      for (int r = 0; r < 4; r++) {
        float gi = sigm(z[0][r] + h2f((ushort)(xs[0] >> (16 * r))));
        float ff = sigm(z[1][r] + h2f((ushort)(xs[1] >> (16 * r))));
        float gg = reluf(z[2][r] + h2f((ushort)(xs[2] >> (16 * r))));
        float oo = sigm(z[3][r] + h2f((ushort)(xs[3] >> (16 * r))));
        c0[r] = ff * c0[r] + gi * gg;
        hs[r] = f2h(oo * reluf(c0[r]));
        wbuf[(quad * 4 + r) * 136 + myu] = __builtin_bit_cast(f16, hs[r]);
      }
      {
        u64 tg = ((u64)(uint)(t + 1)) << 32;
        u64* wb = ringg + (size_t)(t & 7) * 1024 + bb * 512 + (16 * w + l16) * 8 + quad * 2;
        str64(wb,     tg | (u64)((uint)hs[0] | ((uint)hs[1] << 16)));
        str64(wb + 1, tg | (u64)((uint)hs[2] | ((uint)hs[3] << 16)));
      }
    }
  } else {
    // ================= title L1 + dense tail ================================
    f16* wlds = (f16*)smem;                  // W1t @0, U1t @4096 (f16x8 units)
    f16* h0tc = (f16*)(smem + 98304);        // [2][16*136]
    f16* h1db = (f16*)(smem + 107008);       // [2][16*72]
    {
      const uint4* W1tq = (const uint4*)A.W1tf;
      const uint4* U1tq = (const uint4*)A.U1tf;
      uint4* wq = (uint4*)wlds;
      for (int idx = tid; idx < 4096; idx += 256) wq[idx] = W1tq[idx];
      for (int idx = tid; idx < 2048; idx += 256) wq[4096 + idx] = U1tq[idx];
    }
    for (int idx = tid; idx < 1152; idx += 256) h1db[idx] = (f16)0.f;
    float c1[4] = {0.f, 0.f, 0.f, 0.f};
    float bt[4];
#pragma unroll
    for (int gm = 0; gm < 4; gm++) bt[gm] = A.tl1_b[gm * 64 + 16 * w + l16];
    u64* ringg = A.h0tr + (size_t)g * 8192;
    const f16x8* wv8 = (const f16x8*)wlds;
    __syncthreads();

    for (int t = 0; t < 64; t++) {
      const u64* ra[4]; uint nd[4]; u64 rv[4];
      {
        const u64* base = ringg + (size_t)(t & 7) * 1024;
#pragma unroll
        for (int e = 0; e < 4; e++) { ra[e] = base + tid + 256 * e; nd[e] = (uint)(t + 1); }
      }
      poll_recs<4>(ra, nd, rv);
      {
        f16* dst = h0tc + (t & 1) * 2176;
#pragma unroll
        for (int e = 0; e < 4; e++) {
          int idx = tid + 256 * e;
          int q = idx >> 9, rr = idx & 511, uls = rr >> 3, rp = rr & 7;
          uint pay = (uint)rv[e];
          dst[(2 * rp) * 136 + q * 64 + uls]     = __builtin_bit_cast(f16, (ushort)pay);
          dst[(2 * rp + 1) * 136 + q * 64 + uls] = __builtin_bit_cast(f16, (ushort)(pay >> 16));
        }
      }
      __syncthreads();
      if (tid == 0) STRLX(mytag, (uint)(t + 1));    // consumption signal (bp)
      f16x8 af0[4], af1[2];
#pragma unroll
      for (int kf = 0; kf < 4; kf++)
        af0[kf] = *(const f16x8*)&h0tc[(t & 1) * 2176 + l16 * 136 + kf * 32 + quad * 8];
#pragma unroll
      for (int kf = 0; kf < 2; kf++)
        af1[kf] = *(const f16x8*)&h1db[(t & 1) * 1152 + l16 * 72 + kf * 32 + quad * 8];
      f32x4 z[4];
#pragma unroll
      for (int gm = 0; gm < 4; gm++) {
        f32x4 zz = {0.f, 0.f, 0.f, 0.f};
#pragma unroll
        for (int kf = 0; kf < 4; kf++)
          zz = MFMA16(af0[kf], wv8[((gm * 4 + w) * 4 + kf) * 64 + lane], zz);
#pragma unroll
        for (int kf = 0; kf < 2; kf++)
          zz = MFMA16(af1[kf], wv8[4096 + ((gm * 4 + w) * 2 + kf) * 64 + lane], zz);
        z[gm] = zz;
      }
#pragma unroll
      for (int r = 0; r < 4; r++) {
        float gi = sigm(z[0][r] + bt[0]);
        float ff = sigm(z[1][r] + bt[1]);
        float gg = reluf(z[2][r] + bt[2]);
        float oo = sigm(z[3][r] + bt[3]);
        c1[r] = ff * c1[r] + gi * gg;
        h1db[((t + 1) & 1) * 1152 + (quad * 4 + r) * 72 + 16 * w + l16] = (f16)(oo * reluf(c1[r]));
      }
    }
    __syncthreads();
    // dense tail -> feat cols 0..31
    float* zmA = (float*)smem;
    float* zmB = (float*)(smem + 8448);
    const f16* hf = h1db;                    // parity 0
#pragma unroll 1
    for (int e = 0; e < 8; e++) {
      const int idx = tid + 256 * e, sq = idx >> 7, j = idx & 127;
      float a = A.td0b[j];
      for (int k = 0; k < 64; k++) a += (float)hf[sq * 72 + k] * A.td0W[k * 128 + j];
      zmA[sq * 132 + j] = reluf(a);
    }
    __syncthreads();
#pragma unroll 1
    for (int e = 0; e < 4; e++) {
      const int idx = tid + 256 * e, sq = idx >> 6, j = idx & 63;
      float a = A.td1b[j];
      for (int k = 0; k < 128; k++) a += zmA[sq * 132 + k] * A.td1W[k * 64 + j];
      zmB[sq * 68 + j] = reluf(a);
    }
    __syncthreads();
#pragma unroll 1
    for (int e = 0; e < 2; e++) {
      const int idx = tid + 256 * e, sq = idx >> 5, j = idx & 31;
      float a = A.td2b[j];
      for (int k = 0; k < 64; k++) a += zmB[sq * 68 + k] * A.td2W[k * 32 + j];
      A.feat[(g * 16 + sq) * 64 + j] = a;
    }
  }
}

// ---------------- head
__global__ __launch_bounds__(256) void head_kernel(const float* __restrict__ feat,
    const float* __restrict__ L0W, const float* __restrict__ L0b,
    const float* __restrict__ L1W, const float* __restrict__ L1b,
    const float* __restrict__ L2W, const float* __restrict__ L2b,
    const float* __restrict__ L3W, const float* __restrict__ L3b,
    float* __restrict__ out) {
  __shared__ float xb[512];
  __shared__ float y0[2048];
  __shared__ float y1[1024];
  __shared__ float y2[512];
  const int tid = threadIdx.x;
  for (int idx = tid; idx < 512; idx += 256) {
    int b = idx >> 6, d = idx & 63;
    float s = 0.f;
    for (int n = 0; n < 16; n++) s += feat[(b * 16 + n) * 64 + d];
    xb[idx] = s * (1.f / 16.f);
  }
  __syncthreads();
  for (int idx = tid; idx < 2048; idx += 256) {
    int b = idx >> 8, j = idx & 255;
    float a = L0b[j];
    for (int k = 0; k < 64; k++) a += xb[b * 64 + k] * L0W[k * 256 + j];
    y0[idx] = reluf(a);
  }
  __syncthreads();
  for (int idx = tid; idx < 1024; idx += 256) {
    int b = idx >> 7, j = idx & 127;
    float a = L1b[j];
    for (int k = 0; k < 256; k++) a += y0[b * 256 + k] * L1W[k * 128 + j];
    y1[idx] = reluf(a);
  }
  __syncthreads();
  for (int idx = tid; idx < 512; idx += 256) {
    int b = idx >> 6, j = idx & 63;
    float a = L2b[j];
    for (int k = 0; k < 128; k++) a += y1[b * 128 + k] * L2W[k * 64 + j];
    y2[idx] = reluf(a);
  }
  __syncthreads();
  {
    int b = tid >> 5, j = tid & 31;
    float a = L3b[j];
    for (int k = 0; k < 64; k++) a += y2[b * 64 + k] * L3W[k * 32 + j];
    out[b * 32 + j] = 1.f / (1.f + __expf(-a));
  }
}

extern "C" void kernel_launch(void* const* d_in, const int* in_sizes, int n_in,
                              void* d_out, int out_size, void* d_ws, size_t ws_size,
                              hipStream_t stream) {
  const int*   t_tok = (const int*)d_in[0];
  const int*   p_tok = (const int*)d_in[1];
  const float* emb_t = (const float*)d_in[2];
  const float* emb_p = (const float*)d_in[3];
  const float* tl0_W = (const float*)d_in[4];
  const float* tl0_U = (const float*)d_in[5];
  const float* tl0_b = (const float*)d_in[6];
  const float* tl1_W = (const float*)d_in[7];
  const float* tl1_U = (const float*)d_in[8];
  const float* tl1_b = (const float*)d_in[9];
  const float* td0_W = (const float*)d_in[10];
  const float* td0_b = (const float*)d_in[11];
  const float* td1_W = (const float*)d_in[12];
  const float* td1_b = (const float*)d_in[13];
  const float* td2_W = (const float*)d_in[14];
  const float* td2_b = (const float*)d_in[15];
  const float* pl0_W = (const float*)d_in[16];
  const float* pl0_U = (const float*)d_in[17];
  const float* pl0_b = (const float*)d_in[18];
  const float* pl1_W = (const float*)d_in[19];
  const float* pl1_U = (const float*)d_in[20];
  const float* pl1_b = (const float*)d_in[21];
  const float* pl2_W = (const float*)d_in[22];
  const float* pl2_U = (const float*)d_in[23];
  const float* pl2_b = (const float*)d_in[24];
  const float* pd0_W = (const float*)d_in[25];
  const float* pd0_b = (const float*)d_in[26];
  const float* pd1_W = (const float*)d_in[27];
  const float* pd1_b = (const float*)d_in[28];
  const float* pd2_W = (const float*)d_in[29];
  const float* pd2_b = (const float*)d_in[30];
  const float* L0_W  = (const float*)d_in[31];
  const float* L0_b  = (const float*)d_in[32];
  const float* L1_W  = (const float*)d_in[33];
  const float* L1_b  = (const float*)d_in[34];
  const float* L2_W  = (const float*)d_in[35];
  const float* L2_b  = (const float*)d_in[36];
  const float* L3_W  = (const float*)d_in[37];
  const float* L3_b  = (const float*)d_in[38];

  char* ws = (char*)d_ws;
  size_t off = 0;
  auto alloc = [&](size_t bytes) {
    void* ptr = ws + off;
    off += (bytes + 255) & ~(size_t)255;
    return ptr;
  };
  f16* xp2  = (f16*)alloc((size_t)8 * 512 * 4 * 4096 * 2);     // 128 MB
  f16* xt2  = (f16*)alloc((size_t)8 * 64 * 4 * 2048 * 2);      // 8 MB
  f16* Bp   = (f16*)alloc((size_t)256 * 1024 * 2);
  f16* Bt   = (f16*)alloc((size_t)128 * 512 * 2);
  f16* U0f  = (f16*)alloc((size_t)256 * 1024 * 2);
  f16* W1f  = (f16*)alloc((size_t)256 * 512 * 2);
  f16* U1f  = (f16*)alloc((size_t)128 * 512 * 2);
  f16* W2f  = (f16*)alloc((size_t)128 * 256 * 2);
  f16* U2f  = (f16*)alloc((size_t)64 * 256 * 2);
  f16* U0tf = (f16*)alloc((size_t)128 * 512 * 2);
  f16* W1tf = (f16*)alloc((size_t)128 * 256 * 2);
  f16* U1tf = (f16*)alloc((size_t)64 * 256 * 2);
  size_t ringoff = off;
  u64* h0r  = (u64*)alloc((size_t)8 * 16384 * 8);              // 1 MB
  u64* h1r  = (u64*)alloc((size_t)8 * 8192 * 8);               // 512 KB
  u64* h0tr = (u64*)alloc((size_t)8 * 8192 * 8);               // 512 KB
  uint* cnt = (uint*)alloc((size_t)96 * 16 * 4);
  size_t ringlen = off - ringoff;
  float* feat = (float*)alloc((size_t)128 * 64 * 4);

  // rings + cnt MUST be zeroed every replay: stale record tags from a prior
  // replay would false-validate the tag-in-data protocol.
  hipMemsetAsync(ws + ringoff, 0, ringlen, stream);

  pack_bsw<8><<<1024, 256, 0, stream>>>(pl0_W, Bp, 1024);
  pack_bsw<4><<<256, 256, 0, stream>>>(tl0_W, Bt, 512);
  pack_bsw<8><<<1024, 256, 0, stream>>>(pl0_U, U0f, 1024);
  pack_bsw<8><<<512, 256, 0, stream>>>(pl1_W, W1f, 512);
  pack_bsw<4><<<256, 256, 0, stream>>>(pl1_U, U1f, 512);
  pack_bsw<4><<<128, 256, 0, stream>>>(pl2_W, W2f, 256);
  pack_bsw<2><<<64, 256, 0, stream>>>(pl2_U, U2f, 256);
  pack_bsw<4><<<256, 256, 0, stream>>>(tl0_U, U0tf, 512);
  pack_bsw<4><<<128, 256, 0, stream>>>(tl1_W, W1tf, 256);
  pack_bsw<2><<<64, 256, 0, stream>>>(tl1_U, U1tf, 256);
  gemm_xw<512, 256, 8, 1024, 64, 0><<<1024, 256, 0, stream>>>(p_tok, emb_p, Bp, pl0_b, xp2);
  gemm_xw<64, 128, 4, 512, 32, 1><<<128, 256, 0, stream>>>(t_tok, emb_t, Bt, tl0_b, xt2);

  RP ra;
  ra.xp2 = xp2; ra.xt2 = xt2;
  ra.U0f = U0f; ra.W1f = W1f; ra.U1f = U1f; ra.W2f = W2f; ra.U2f = U2f;
  ra.U0tf = U0tf; ra.W1tf = W1tf; ra.U1tf = U1tf;
  ra.pl1_b = pl1_b; ra.pl2_b = pl2_b; ra.tl1_b = tl1_b;
  ra.pd0W = pd0_W; ra.pd0b = pd0_b; ra.pd1W = pd1_W; ra.pd1b = pd1_b;
  ra.pd2W = pd2_W; ra.pd2b = pd2_b;
  ra.td0W = td0_W; ra.td0b = td0_b; ra.td1W = td1_W; ra.td1b = td1_b;
  ra.td2W = td2_W; ra.td2b = td2_b;
  ra.h0r = h0r; ra.h1r = h1r; ra.h0tr = h0tr; ra.cnt = cnt;
  ra.feat = feat;
  recur_pipe<<<96, 256, 0, stream>>>(ra);

  head_kernel<<<1, 256, 0, stream>>>(feat, L0_W, L0_b, L1_W, L1_b, L2_W, L2_b,
                                     L3_W, L3_b, (float*)d_out);
}